// Round 1
// baseline (649.291 us; speedup 1.0000x reference)
//
#include <hip/hip_runtime.h>
#include <math.h>

// RNN_197568496340: 6-layer ReLU RNN (T=1024,B=2048,IN=2,H=20) + FC(20->2) + log_softmax.
//
// Strategy: persistent pipelined blocks. 256 blocks (1/CU), each owns 8 batch
// elements and runs the ENTIRE time loop for all 6 layers + output head.
// Wave w (0..5) = layer w; wave 6 = FC/log_softmax output wave.
// At wall-step s, layer l computes t = s-l  => sequential chain is T+L ~ 1030
// barrier steps instead of T*L = 6144. Inter-layer data + recurrent h flow
// through a double-buffered LDS ring (parity = s&1). Weights live in VGPRs.

#define TT 1024
#define BB 2048
#define INs 2
#define HH 20
#define LL 6
#define CC 2
#define CB 8                  // batch elements per block
#define NBLK (BB / CB)        // 256 blocks -> 1 per CU
#define NTHR 448              // 7 waves
#define NSTEPS (TT + LL)      // 1030 wall-steps (out wave last active at s=1029)

__device__ __forceinline__ void ld20(const float* p, float* d) {
    const float4* v = (const float4*)p;
#pragma unroll
    for (int q = 0; q < 5; ++q) {
        float4 t = v[q];
        d[4 * q + 0] = t.x; d[4 * q + 1] = t.y;
        d[4 * q + 2] = t.z; d[4 * q + 3] = t.w;
    }
}

__global__ __launch_bounds__(NTHR, 1)
void rnn_fused(const float* __restrict__ x,
               const float* __restrict__ Wih0,   // [20][2]
               const float* __restrict__ Wih,    // [5][20][20]
               const float* __restrict__ Whh,    // [6][20][20]
               const float* __restrict__ bih,    // [6][20]
               const float* __restrict__ bhh,    // [6][20]
               const float* __restrict__ fcw,    // [2][20]
               const float* __restrict__ fcb,    // [2]
               float* __restrict__ out)          // [1024][2048][2]
{
    // buf[l][parity][b][j] : output of layer l at parity (s&1)
    __shared__ float buf[LL][2][CB][HH];   // 7680 B

    const int tid  = threadIdx.x;
    const int wave = tid >> 6;
    const int lane = tid & 63;
    const int bg0  = blockIdx.x * CB;

    // zero-init LDS (h(t=-1)=0 for every layer, both parities)
    for (int i = tid; i < LL * 2 * CB * HH; i += NTHR)
        ((float*)buf)[i] = 0.0f;
    __syncthreads();

    if (wave < LL) {
        // ---------------- layer wave ----------------
        const int l  = wave;
        const int bl = lane >> 3;        // 0..7 : local batch element
        const int jg = lane & 7;         // 0..7 : neuron group
        const int j0 = jg * 3;           // neurons j0..j0+2 (valid if <20)

        // register-resident weights (rows clamped for the tail lanes; their
        // results are never stored)
        float whw[3][HH];
        float wiw[3][HH];                // layers >=1
        float wi0[3][INs];               // layer 0
        float bias[3];
#pragma unroll
        for (int r = 0; r < 3; ++r) {
            int j = j0 + r; if (j >= HH) j = HH - 1;
            bias[r] = bih[l * HH + j] + bhh[l * HH + j];
            ld20(&Whh[(l * HH + j) * HH], whw[r]);
            if (l == 0) {
                wi0[r][0] = Wih0[j * INs + 0];
                wi0[r][1] = Wih0[j * INs + 1];
            } else {
                ld20(&Wih[((l - 1) * HH + j) * HH], wiw[r]);
            }
        }

        // x prefetch (layer 0 only): x[t][b][0..1] as one float2
        float2 xc = make_float2(0.f, 0.f), xn = make_float2(0.f, 0.f);
        const float2* xp = (const float2*)x;
        if (l == 0) xc = xp[(size_t)0 * BB + bg0 + bl];

        float* const mybase = &buf[l][0][bl][0];                    // + parity*CB*HH
        const float* const inbase = (l > 0) ? &buf[l - 1][0][bl][0] : nullptr;

        for (int s = 0; s < NSTEPS; ++s) {
            const int t = s - l;
            if (t >= 0 && t < TT) {
                const int rp = ((s + 1) & 1) * (CB * HH);   // read parity ((s-1)&1)
                const int wp = (s & 1) * (CB * HH);

                float hv[HH];
                ld20(mybase + rp, hv);                      // h_{t-1} (own output)

                float a0 = bias[0], a1 = bias[1], a2 = bias[2];

                if (l == 0) {
                    a0 += wi0[0][0] * xc.x + wi0[0][1] * xc.y;
                    a1 += wi0[1][0] * xc.x + wi0[1][1] * xc.y;
                    a2 += wi0[2][0] * xc.x + wi0[2][1] * xc.y;
                    if (t + 1 < TT) xn = xp[(size_t)(t + 1) * BB + bg0 + bl];
                } else {
                    float iv[HH];
                    ld20(inbase + rp, iv);                  // layer l-1 output at t
#pragma unroll
                    for (int k = 0; k < HH; ++k) {
                        a0 = fmaf(wiw[0][k], iv[k], a0);
                        a1 = fmaf(wiw[1][k], iv[k], a1);
                        a2 = fmaf(wiw[2][k], iv[k], a2);
                    }
                }
#pragma unroll
                for (int k = 0; k < HH; ++k) {
                    a0 = fmaf(whw[0][k], hv[k], a0);
                    a1 = fmaf(whw[1][k], hv[k], a1);
                    a2 = fmaf(whw[2][k], hv[k], a2);
                }
                a0 = fmaxf(a0, 0.f);
                a1 = fmaxf(a1, 0.f);
                a2 = fmaxf(a2, 0.f);

                float* wpp = mybase + wp;
                if (j0 + 0 < HH) wpp[j0 + 0] = a0;
                if (j0 + 1 < HH) wpp[j0 + 1] = a1;
                if (j0 + 2 < HH) wpp[j0 + 2] = a2;

                if (l == 0) xc = xn;
            }
            __syncthreads();
        }
    } else {
        // ---------------- output wave: FC(20->2) + log_softmax ----------------
        float fw0[HH], fw1[HH];
#pragma unroll
        for (int k = 0; k < HH; ++k) { fw0[k] = fcw[k]; fw1[k] = fcw[HH + k]; }
        const float fb0 = fcb[0], fb1 = fcb[1];

        const int bl = (lane < CB) ? lane : 0;
        const float* const hbase = &buf[LL - 1][0][bl][0];
        float2* const op = (float2*)out;

        for (int s = 0; s < NSTEPS; ++s) {
            const int t = s - LL;
            if (t >= 0 && t < TT && lane < CB) {
                const int rp = ((s + 1) & 1) * (CB * HH);   // layer-5 output at t
                float hv[HH];
                ld20(hbase + rp, hv);
                float l0 = fb0, l1 = fb1;
#pragma unroll
                for (int k = 0; k < HH; ++k) {
                    l0 = fmaf(hv[k], fw0[k], l0);
                    l1 = fmaf(hv[k], fw1[k], l1);
                }
                const float m   = fmaxf(l0, l1);
                const float lse = m + __logf(__expf(l0 - m) + __expf(l1 - m));
                float2 o; o.x = l0 - lse; o.y = l1 - lse;
                op[(size_t)t * BB + bg0 + bl] = o;
            }
            __syncthreads();
        }
    }
}

extern "C" void kernel_launch(void* const* d_in, const int* in_sizes, int n_in,
                              void* d_out, int out_size, void* d_ws, size_t ws_size,
                              hipStream_t stream) {
    const float* x    = (const float*)d_in[0];
    const float* Wih0 = (const float*)d_in[1];
    const float* Wih  = (const float*)d_in[2];
    const float* Whh  = (const float*)d_in[3];
    const float* bih  = (const float*)d_in[4];
    const float* bhh  = (const float*)d_in[5];
    const float* fcw  = (const float*)d_in[6];
    const float* fcb  = (const float*)d_in[7];
    float* out = (float*)d_out;

    rnn_fused<<<dim3(NBLK), dim3(NTHR), 0, stream>>>(
        x, Wih0, Wih, Whh, bih, bhh, fcw, fcb, out);
}